// Round 2
// baseline (6735.326 us; speedup 1.0000x reference)
//
#include <hip/hip_runtime.h>
#include <math.h>

#define DD 128
#define NNODES 100000
#define NEDGES 600000

typedef __attribute__((ext_vector_type(8))) short short8;
typedef __attribute__((ext_vector_type(4))) float f32x4;

__device__ inline float bf2f(unsigned short u){ return __uint_as_float(((unsigned int)u)<<16); }
__device__ inline float bflo(unsigned int u){ return __uint_as_float(u<<16); }
__device__ inline float bfhi(unsigned int u){ return __uint_as_float(u & 0xffff0000u); }
__device__ inline unsigned short f2bf(float f){          // RNE fp32->bf16
    unsigned int i = __float_as_uint(f);
    unsigned int r = (i + 0x7fffu + ((i>>16)&1u)) >> 16;
    return (unsigned short)r;
}
__device__ inline short8 cvt8(const float* __restrict__ p){  // 8 fp32 -> bf16x8
    f32x4 a = *(const f32x4*)p;
    f32x4 b = *(const f32x4*)(p+4);
    short8 t;
    t[0]=(short)f2bf(a[0]); t[1]=(short)f2bf(a[1]); t[2]=(short)f2bf(a[2]); t[3]=(short)f2bf(a[3]);
    t[4]=(short)f2bf(b[0]); t[5]=(short)f2bf(b[1]); t[6]=(short)f2bf(b[2]); t[7]=(short)f2bf(b[3]);
    return t;
}
__device__ inline float fast_tanh(float x){
    x = fminf(10.f, fmaxf(-10.f, x));
    float e = __expf(2.f*x);
    return (e - 1.f) / (e + 1.f);
}

// ---- K0: convert att_w1 fp32 -> bf16 once (tiny) -----------------------------
__global__ __launch_bounds__(256) void k_cvt(const float* __restrict__ in,
                                             unsigned short* __restrict__ out, int n4)
{
    int gid = blockIdx.x*256 + threadIdx.x;
    if (gid >= n4) return;
    f32x4 v = ((const f32x4*)in)[gid];
    ushort4 o;
    o.x=f2bf(v[0]); o.y=f2bf(v[1]); o.z=f2bf(v[2]); o.w=f2bf(v[3]);
    ((ushort4*)out)[gid] = o;
}

// ---- K1: f = feat @ W^T  (fp32 in -> bf16 MFMA -> bf16 out) ------------------
__global__ __launch_bounds__(256) void k_transform(
    const float* __restrict__ feat, const float* __restrict__ W,
    unsigned short* __restrict__ f_out)
{
    int wid = blockIdx.x*4 + (threadIdx.x>>6);
    if (wid >= NNODES/16) return;
    int lane = threadIdx.x & 63;
    int m = lane & 15, quad = lane >> 4;
    int n0 = wid*16;

    short8 a[4];                                   // A[m][k], k=ks*32+quad*8+j
    const float* arow = feat + (size_t)(n0+m)*DD;
    #pragma unroll
    for (int ks=0; ks<4; ++ks) a[ks] = cvt8(arow + ks*32 + quad*8);

    #pragma unroll
    for (int ct=0; ct<8; ++ct){
        f32x4 acc = {0.f,0.f,0.f,0.f};
        const float* brow = W + (size_t)(ct*16+m)*DD;   // B[k][n]=W[n][k]
        #pragma unroll
        for (int ks=0; ks<4; ++ks){
            short8 b = cvt8(brow + ks*32 + quad*8);
            acc = __builtin_amdgcn_mfma_f32_16x16x32_bf16(a[ks], b, acc, 0,0,0);
        }
        int col = ct*16 + m;
        #pragma unroll
        for (int i=0;i<4;++i)                      // C/D: col=lane&15, row=quad*4+reg
            f_out[(size_t)(n0+quad*4+i)*DD + col] = f2bf(acc[i]);
    }
}

// ---- K2: edge gather (bf16 f) + fp32 atomic scatter --------------------------
__global__ __launch_bounds__(256) void k_edge_agg(
    const unsigned short* __restrict__ f,
    const int* __restrict__ src, const int* __restrict__ dst,
    const float* __restrict__ ew,            // fp32 weights or null
    float* __restrict__ sum,                 // fp32 [N,128] accumulator (d_out)
    float* __restrict__ cnt)                 // fp32 [N] or null
{
    int gid = blockIdx.x*256 + threadIdx.x;
    int e = gid >> 4;
    if (e >= NEDGES) return;
    int c0 = (gid & 15) << 3;                // 8 elements per lane
    int s = src[e], d = dst[e];
    uint4 v = *(const uint4*)(f + (size_t)s*DD + c0);
    float w = (ew != nullptr) ? ew[e] : 1.0f;
    float vals[8];
    vals[0]=bflo(v.x); vals[1]=bfhi(v.x); vals[2]=bflo(v.y); vals[3]=bfhi(v.y);
    vals[4]=bflo(v.z); vals[5]=bfhi(v.z); vals[6]=bflo(v.w); vals[7]=bfhi(v.w);
    float* base = sum + (size_t)d*DD + c0;
    #pragma unroll
    for (int i=0;i<8;++i) atomicAdd(base+i, w*vals[i]);
    if (cnt && c0 == 0) atomicAdd(cnt + d, 1.0f);
}

// ---- K3: z = acc / max(cnt,1), fp32 -> bf16 ----------------------------------
__global__ __launch_bounds__(256) void k_divconv(
    const float* __restrict__ acc, const float* __restrict__ cnt,
    unsigned short* __restrict__ z)
{
    int gid = blockIdx.x*256 + threadIdx.x;      // one per 4 elements
    if (gid >= NNODES*DD/4) return;
    float inv = 1.f;
    if (cnt) { int row = gid >> 5; inv = 1.f / fmaxf(cnt[row], 1.f); }
    f32x4 v = ((const f32x4*)acc)[gid];
    ushort4 o;
    o.x=f2bf(v[0]*inv); o.y=f2bf(v[1]*inv); o.z=f2bf(v[2]*inv); o.w=f2bf(v[3]*inv);
    ((ushort4*)z)[gid] = o;
}

// ---- K4: w[r] = sum_n w2 . tanh(W1 z + b1) -----------------------------------
__global__ __launch_bounds__(256) void k_att(
    const unsigned short* __restrict__ zg, const unsigned short* __restrict__ zt,
    const unsigned short* __restrict__ zc,
    const unsigned short* __restrict__ w1,   // bf16 [512,128]
    const float* __restrict__ b1,            // fp32 [512]
    const float* __restrict__ w2,            // fp32 [512]
    float* __restrict__ w_part)              // fp32 [3]
{
    int wid = blockIdx.x*4 + (threadIdx.x>>6);
    if (wid >= 3*(NNODES/32)) return;
    int lane = threadIdx.x & 63;
    int m = lane & 15, quad = lane >> 4;
    int rel = wid / (NNODES/32);
    int n0 = (wid % (NNODES/32)) * 32;
    const unsigned short* z = (rel==0) ? zg : (rel==1) ? zt : zc;

    short8 a[2][4];
    #pragma unroll
    for (int rt=0; rt<2; ++rt){
        const short8* zr = (const short8*)(z + (size_t)(n0+rt*16+m)*DD);
        #pragma unroll
        for (int ks=0; ks<4; ++ks) a[rt][ks] = zr[ks*4 + quad];
    }

    float s_all = 0.f;
    #pragma unroll
    for (int chunk=0; chunk<4; ++chunk){
        #pragma unroll
        for (int ct=0; ct<8; ++ct){
            int col = chunk*128 + ct*16 + m;
            f32x4 acc0 = {0.f,0.f,0.f,0.f}, acc1 = {0.f,0.f,0.f,0.f};
            const short8* brow = (const short8*)(w1 + (size_t)col*DD);
            #pragma unroll
            for (int ks=0; ks<4; ++ks){
                short8 b = brow[ks*4 + quad];
                acc0 = __builtin_amdgcn_mfma_f32_16x16x32_bf16(a[0][ks], b, acc0, 0,0,0);
                acc1 = __builtin_amdgcn_mfma_f32_16x16x32_bf16(a[1][ks], b, acc1, 0,0,0);
            }
            float bb = b1[col];
            float ww = w2[col];
            #pragma unroll
            for (int i=0;i<4;++i){
                s_all += ww * fast_tanh(acc0[i] + bb);
                s_all += ww * fast_tanh(acc1[i] + bb);
            }
        }
    }
    #pragma unroll
    for (int off=32; off; off>>=1) s_all += __shfl_xor(s_all, off);
    if (lane == 0) atomicAdd(&w_part[rel], s_all);
}

// ---- K5: softmax(3) + fuse + leaky relu, fp32 out ----------------------------
__global__ __launch_bounds__(256) void k_final(
    const unsigned short* __restrict__ z0, const unsigned short* __restrict__ z1,
    const unsigned short* __restrict__ z2,
    const float* __restrict__ w_part, float* __restrict__ out)
{
    int gid = blockIdx.x*256 + threadIdx.x;      // one per 4 elements
    if (gid >= NNODES*DD/4) return;
    const float invN = 1.f / (float)NNODES;
    float w0 = w_part[0]*invN, w1 = w_part[1]*invN, w2 = w_part[2]*invN;
    float mx = fmaxf(w0, fmaxf(w1, w2));
    float e0 = __expf(w0-mx), e1 = __expf(w1-mx), e2 = __expf(w2-mx);
    float inv = 1.f/(e0+e1+e2);
    float b0 = e0*inv, b1 = e1*inv, b2 = e2*inv;
    ushort4 g = ((const ushort4*)z0)[gid];
    ushort4 t = ((const ushort4*)z1)[gid];
    ushort4 c = ((const ushort4*)z2)[gid];
    float gv[4] = {bf2f(g.x),bf2f(g.y),bf2f(g.z),bf2f(g.w)};
    float tv[4] = {bf2f(t.x),bf2f(t.y),bf2f(t.z),bf2f(t.w)};
    float cv[4] = {bf2f(c.x),bf2f(c.y),bf2f(c.z),bf2f(c.w)};
    f32x4 o;
    #pragma unroll
    for (int i=0;i<4;++i){
        float x = b0*gv[i] + b1*tv[i] + b2*cv[i];
        o[i] = (x > 0.f) ? x : 0.2f*x;
    }
    ((f32x4*)out)[gid] = o;
}

extern "C" void kernel_launch(void* const* d_in, const int* in_sizes, int n_in,
                              void* d_out, int out_size, void* d_ws, size_t ws_size,
                              hipStream_t stream)
{
    const float* feat = (const float*)d_in[0];
    const float* W    = (const float*)d_in[1];
    const float* aw1  = (const float*)d_in[2];
    const float* ab1  = (const float*)d_in[3];
    const float* aw2  = (const float*)d_in[4];
    const float* tw   = (const float*)d_in[5];
    const int* geo_src   = (const int*)d_in[6];
    const int* geo_dst   = (const int*)d_in[7];
    const int* cat_src   = (const int*)d_in[8];
    const int* cat_dst   = (const int*)d_in[9];
    const int* trans_src = (const int*)d_in[10];
    const int* trans_dst = (const int*)d_in[11];

    // ws layout (~103.3 MB): cnt_geo | cnt_cat | w_part | w1_bf | z0 | z1 | z2 | f_bf
    char* ws = (char*)d_ws;
    float* cnt_geo = (float*)ws;
    float* cnt_cat = cnt_geo + NNODES;
    float* w_part  = cnt_cat + NNODES;
    unsigned short* w1_bf = (unsigned short*)(w_part + 64);
    unsigned short* z0   = w1_bf + 512*DD;
    unsigned short* z1   = z0 + (size_t)NNODES*DD;
    unsigned short* z2   = z1 + (size_t)NNODES*DD;
    unsigned short* f_bf = z2 + (size_t)NNODES*DD;
    float* acc = (float*)d_out;                  // fp32 [N,128] accumulator, reused 3x

    size_t small_bytes = (char*)w1_bf - ws;      // cnt arrays + w_part
    size_t acc_bytes = (size_t)NNODES*DD*4;

    hipMemsetAsync(d_ws, 0, small_bytes, stream);
    hipMemsetAsync(d_out, 0, acc_bytes, stream);

    k_cvt<<<64, 256, 0, stream>>>(aw1, w1_bf, 512*DD/4);
    k_transform<<<(NNODES/16 + 3)/4, 256, 0, stream>>>(feat, W, f_bf);

    int eg = (NEDGES*16)/256;                    // 37500
    int dg = (NNODES*DD/4 + 255)/256;            // 12500

    k_edge_agg<<<eg, 256, 0, stream>>>(f_bf, geo_src, geo_dst, nullptr, acc, cnt_geo);
    k_divconv<<<dg, 256, 0, stream>>>(acc, cnt_geo, z0);
    hipMemsetAsync(d_out, 0, acc_bytes, stream);

    k_edge_agg<<<eg, 256, 0, stream>>>(f_bf, cat_src, cat_dst, nullptr, acc, cnt_cat);
    k_divconv<<<dg, 256, 0, stream>>>(acc, cnt_cat, z1);
    hipMemsetAsync(d_out, 0, acc_bytes, stream);

    k_edge_agg<<<eg, 256, 0, stream>>>(f_bf, trans_src, trans_dst, tw, acc, nullptr);
    k_divconv<<<dg, 256, 0, stream>>>(acc, nullptr, z2);

    k_att<<<(3*(NNODES/32) + 3)/4, 256, 0, stream>>>(z0, z1, z2, w1_bf, ab1, aw2, w_part);

    k_final<<<dg, 256, 0, stream>>>(z0, z1, z2, w_part, (float*)d_out);
}

// Round 3
// 742.140 us; speedup vs baseline: 9.0755x; 9.0755x over previous
//
#include <hip/hip_runtime.h>
#include <math.h>

#define DD 128
#define NNODES 100000
#define NEDGES 600000
#define NREL 3
#define MTOT (NREL*NNODES)

typedef __attribute__((ext_vector_type(8))) short short8;
typedef __attribute__((ext_vector_type(4))) float f32x4;

__device__ inline float bf2f(unsigned short u){ return __uint_as_float(((unsigned int)u)<<16); }
__device__ inline float bflo(unsigned int u){ return __uint_as_float(u<<16); }
__device__ inline float bfhi(unsigned int u){ return __uint_as_float(u & 0xffff0000u); }
__device__ inline unsigned short f2bf(float f){          // RNE fp32->bf16
    unsigned int i = __float_as_uint(f);
    unsigned int r = (i + 0x7fffu + ((i>>16)&1u)) >> 16;
    return (unsigned short)r;
}
__device__ inline unsigned int pack2(float lo, float hi){
    return (unsigned int)f2bf(lo) | ((unsigned int)f2bf(hi) << 16);
}
__device__ inline short8 cvt8(const float* __restrict__ p){  // 8 fp32 -> bf16x8
    f32x4 a = *(const f32x4*)p;
    f32x4 b = *(const f32x4*)(p+4);
    short8 t;
    t[0]=(short)f2bf(a[0]); t[1]=(short)f2bf(a[1]); t[2]=(short)f2bf(a[2]); t[3]=(short)f2bf(a[3]);
    t[4]=(short)f2bf(b[0]); t[5]=(short)f2bf(b[1]); t[6]=(short)f2bf(b[2]); t[7]=(short)f2bf(b[3]);
    return t;
}
__device__ inline float fast_tanh(float x){
    x = fminf(10.f, fmaxf(-10.f, x));
    float e = __expf(2.f*x);
    return (e - 1.f) / (e + 1.f);
}

// ---- K0: convert att_w1 fp32 -> bf16 -----------------------------------------
__global__ __launch_bounds__(256) void k_cvt(const float* __restrict__ in,
                                             unsigned short* __restrict__ out, int n4)
{
    int gid = blockIdx.x*256 + threadIdx.x;
    if (gid >= n4) return;
    f32x4 v = ((const f32x4*)in)[gid];
    ushort4 o;
    o.x=f2bf(v[0]); o.y=f2bf(v[1]); o.z=f2bf(v[2]); o.w=f2bf(v[3]);
    ((ushort4*)out)[gid] = o;
}

// ---- K1: f = feat @ W^T  (fp32 in -> bf16 MFMA -> bf16 out) ------------------
__global__ __launch_bounds__(256) void k_transform(
    const float* __restrict__ feat, const float* __restrict__ W,
    unsigned short* __restrict__ f_out)
{
    int wid = blockIdx.x*4 + (threadIdx.x>>6);
    if (wid >= NNODES/16) return;
    int lane = threadIdx.x & 63;
    int m = lane & 15, quad = lane >> 4;
    int n0 = wid*16;

    short8 a[4];                                   // A[m][k], k=ks*32+quad*8+j
    const float* arow = feat + (size_t)(n0+m)*DD;
    #pragma unroll
    for (int ks=0; ks<4; ++ks) a[ks] = cvt8(arow + ks*32 + quad*8);

    #pragma unroll
    for (int ct=0; ct<8; ++ct){
        f32x4 acc = {0.f,0.f,0.f,0.f};
        const float* brow = W + (size_t)(ct*16+m)*DD;   // B[k][n]=W[n][k]
        #pragma unroll
        for (int ks=0; ks<4; ++ks){
            short8 b = cvt8(brow + ks*32 + quad*8);
            acc = __builtin_amdgcn_mfma_f32_16x16x32_bf16(a[ks], b, acc, 0,0,0);
        }
        int col = ct*16 + m;
        #pragma unroll
        for (int i=0;i<4;++i)                      // C/D: col=lane&15, row=quad*4+reg
            f_out[(size_t)(n0+quad*4+i)*DD + col] = f2bf(acc[i]);
    }
}

// ---- CSR build: histogram ----------------------------------------------------
__global__ __launch_bounds__(256) void k_hist(const int* __restrict__ dst,
                                              int* __restrict__ cnt_rel)
{
    int e = blockIdx.x*256 + threadIdx.x;
    if (e >= NEDGES) return;
    atomicAdd(&cnt_rel[dst[e]], 1);
}

// ---- CSR build: two-level exclusive scan over cnt[MTOT] ----------------------
__global__ __launch_bounds__(256) void k_scan1(const int* __restrict__ cnt,
                                               int* __restrict__ offs,
                                               int* __restrict__ bsum)
{
    __shared__ int sm[256];
    int t = threadIdx.x;
    int base = blockIdx.x*1024 + t*4;
    int v[4];
    #pragma unroll
    for (int i=0;i<4;++i){ int idx=base+i; v[i] = (idx<MTOT)? cnt[idx] : 0; }
    int tot = v[0]+v[1]+v[2]+v[3];
    sm[t] = tot; __syncthreads();
    for (int off=1; off<256; off<<=1){
        int x = (t>=off)? sm[t-off] : 0;
        __syncthreads();
        sm[t] += x;
        __syncthreads();
    }
    int run = (t>0)? sm[t-1] : 0;                 // exclusive within block
    if (t==255) bsum[blockIdx.x] = sm[255];
    #pragma unroll
    for (int i=0;i<4;++i){ int idx=base+i; if (idx<MTOT) offs[idx]=run; run += v[i]; }
}

__global__ __launch_bounds__(512) void k_scan2(int* __restrict__ bsum, int nb)
{
    __shared__ int sm[512];
    int t = threadIdx.x;
    sm[t] = (t<nb)? bsum[t] : 0; __syncthreads();
    for (int off=1; off<512; off<<=1){
        int x = (t>=off)? sm[t-off] : 0;
        __syncthreads();
        sm[t] += x;
        __syncthreads();
    }
    if (t<nb) bsum[t] = (t>0)? sm[t-1] : 0;       // exclusive
}

__global__ __launch_bounds__(256) void k_scan3(int* __restrict__ offs,
                                               int* __restrict__ cursor,
                                               const int* __restrict__ bsum)
{
    int g = blockIdx.x*256 + threadIdx.x;
    if (g >= MTOT) return;
    int v = offs[g] + bsum[g>>10];
    offs[g] = v;
    cursor[g] = v;
}

// ---- CSR build: fill edge lists ---------------------------------------------
__global__ __launch_bounds__(256) void k_fill(
    const int* __restrict__ src, const int* __restrict__ dst,
    const float* __restrict__ w,            // null for unweighted
    int* __restrict__ cursor_rel,           // cursor + rel*N
    int* __restrict__ es, float* __restrict__ ewt)
{
    int e = blockIdx.x*256 + threadIdx.x;
    if (e >= NEDGES) return;
    int d = dst[e];
    int pos = atomicAdd(&cursor_rel[d], 1);
    es[pos] = src[e];
    if (w) ewt[pos - 2*NEDGES] = w[e];      // weighted relation occupies [2E,3E)
}

// ---- K2: gather-side aggregation, one 16-lane group per (rel,node) -----------
__global__ __launch_bounds__(256) void k_agg(
    const unsigned short* __restrict__ f,   // bf16 [N,128]
    const int* __restrict__ es, const float* __restrict__ ewt,
    const int* __restrict__ offs, const int* __restrict__ cnt,
    unsigned short* __restrict__ z)         // bf16 [3,N,128]: geo|cat|trans
{
    int gid = blockIdx.x*256 + threadIdx.x;
    int g = gid >> 4;                        // (rel,node) slot in [0, 3N)
    if (g >= MTOT) return;
    int c = gid & 15;                        // 8-col chunk
    int rel = g / NNODES;                    // 0 geo, 1 cat, 2 trans (weighted)
    int start = offs[g];
    int deg   = cnt[g];

    float a0=0,a1=0,a2=0,a3=0,a4=0,a5=0,a6=0,a7=0;
    for (int i=0; i<deg; ++i){
        int s = es[start+i];
        float w = (rel==2) ? ewt[start+i - 2*NEDGES] : 1.f;
        uint4 v = *(const uint4*)(f + (size_t)s*DD + c*8);
        a0 += w*bflo(v.x); a1 += w*bfhi(v.x);
        a2 += w*bflo(v.y); a3 += w*bfhi(v.y);
        a4 += w*bflo(v.z); a5 += w*bfhi(v.z);
        a6 += w*bflo(v.w); a7 += w*bfhi(v.w);
    }
    float sc = (rel<2) ? 1.f/fmaxf((float)deg, 1.f) : 1.f;
    uint4 o;
    o.x = pack2(a0*sc, a1*sc);
    o.y = pack2(a2*sc, a3*sc);
    o.z = pack2(a4*sc, a5*sc);
    o.w = pack2(a6*sc, a7*sc);
    *(uint4*)(z + (size_t)g*DD + c*8) = o;
}

// ---- K4: w[r] = sum_n w2 . tanh(W1 z + b1) -----------------------------------
__global__ __launch_bounds__(256) void k_att(
    const unsigned short* __restrict__ zg, const unsigned short* __restrict__ zt,
    const unsigned short* __restrict__ zc,
    const unsigned short* __restrict__ w1,   // bf16 [512,128]
    const float* __restrict__ b1,            // fp32 [512]
    const float* __restrict__ w2,            // fp32 [512]
    float* __restrict__ w_part)              // fp32 [3]
{
    int wid = blockIdx.x*4 + (threadIdx.x>>6);
    if (wid >= 3*(NNODES/32)) return;
    int lane = threadIdx.x & 63;
    int m = lane & 15, quad = lane >> 4;
    int rel = wid / (NNODES/32);
    int n0 = (wid % (NNODES/32)) * 32;
    const unsigned short* z = (rel==0) ? zg : (rel==1) ? zt : zc;

    short8 a[2][4];
    #pragma unroll
    for (int rt=0; rt<2; ++rt){
        const short8* zr = (const short8*)(z + (size_t)(n0+rt*16+m)*DD);
        #pragma unroll
        for (int ks=0; ks<4; ++ks) a[rt][ks] = zr[ks*4 + quad];
    }

    float s_all = 0.f;
    #pragma unroll
    for (int chunk=0; chunk<4; ++chunk){
        #pragma unroll
        for (int ct=0; ct<8; ++ct){
            int col = chunk*128 + ct*16 + m;
            f32x4 acc0 = {0.f,0.f,0.f,0.f}, acc1 = {0.f,0.f,0.f,0.f};
            const short8* brow = (const short8*)(w1 + (size_t)col*DD);
            #pragma unroll
            for (int ks=0; ks<4; ++ks){
                short8 b = brow[ks*4 + quad];
                acc0 = __builtin_amdgcn_mfma_f32_16x16x32_bf16(a[0][ks], b, acc0, 0,0,0);
                acc1 = __builtin_amdgcn_mfma_f32_16x16x32_bf16(a[1][ks], b, acc1, 0,0,0);
            }
            float bb = b1[col];
            float ww = w2[col];
            #pragma unroll
            for (int i=0;i<4;++i){
                s_all += ww * fast_tanh(acc0[i] + bb);
                s_all += ww * fast_tanh(acc1[i] + bb);
            }
        }
    }
    #pragma unroll
    for (int off=32; off; off>>=1) s_all += __shfl_xor(s_all, off);
    if (lane == 0) atomicAdd(&w_part[rel], s_all);
}

// ---- K5: softmax(3) + fuse + leaky relu, fp32 out ----------------------------
__global__ __launch_bounds__(256) void k_final(
    const unsigned short* __restrict__ z0, const unsigned short* __restrict__ z1,
    const unsigned short* __restrict__ z2,
    const float* __restrict__ w_part, float* __restrict__ out)
{
    int gid = blockIdx.x*256 + threadIdx.x;      // one per 4 elements
    if (gid >= NNODES*DD/4) return;
    const float invN = 1.f / (float)NNODES;
    float w0 = w_part[0]*invN, w1 = w_part[1]*invN, w2 = w_part[2]*invN;
    float mx = fmaxf(w0, fmaxf(w1, w2));
    float e0 = __expf(w0-mx), e1 = __expf(w1-mx), e2 = __expf(w2-mx);
    float inv = 1.f/(e0+e1+e2);
    float b0 = e0*inv, b1 = e1*inv, b2 = e2*inv;
    ushort4 g = ((const ushort4*)z0)[gid];
    ushort4 t = ((const ushort4*)z1)[gid];
    ushort4 c = ((const ushort4*)z2)[gid];
    f32x4 o;
    float gv[4] = {bf2f(g.x),bf2f(g.y),bf2f(g.z),bf2f(g.w)};
    float tv[4] = {bf2f(t.x),bf2f(t.y),bf2f(t.z),bf2f(t.w)};
    float cv[4] = {bf2f(c.x),bf2f(c.y),bf2f(c.z),bf2f(c.w)};
    #pragma unroll
    for (int i=0;i<4;++i){
        float x = b0*gv[i] + b1*tv[i] + b2*cv[i];
        o[i] = (x > 0.f) ? x : 0.2f*x;
    }
    ((f32x4*)out)[gid] = o;
}

extern "C" void kernel_launch(void* const* d_in, const int* in_sizes, int n_in,
                              void* d_out, int out_size, void* d_ws, size_t ws_size,
                              hipStream_t stream)
{
    const float* feat = (const float*)d_in[0];
    const float* W    = (const float*)d_in[1];
    const float* aw1  = (const float*)d_in[2];
    const float* ab1  = (const float*)d_in[3];
    const float* aw2  = (const float*)d_in[4];
    const float* tw   = (const float*)d_in[5];
    const int* geo_src   = (const int*)d_in[6];
    const int* geo_dst   = (const int*)d_in[7];
    const int* cat_src   = (const int*)d_in[8];
    const int* cat_dst   = (const int*)d_in[9];
    const int* trans_src = (const int*)d_in[10];
    const int* trans_dst = (const int*)d_in[11];

    // ws layout (~91 MB): cnt | w_part | offs | cursor | bsum | w1_bf | es | ewt | z
    char* ws = (char*)d_ws;
    int*   cnt    = (int*)ws;                        // [3N]
    float* w_part = (float*)(cnt + MTOT);            // [64]
    int*   offs   = (int*)(w_part + 64);             // [3N]
    int*   cursor = offs + MTOT;                     // [3N]
    int*   bsum   = cursor + MTOT;                   // [512]
    unsigned short* w1_bf = (unsigned short*)(bsum + 512);       // [512*128]
    int*   es     = (int*)(w1_bf + 512*DD);          // [3E]
    float* ewt    = (float*)(es + NREL*NEDGES);      // [E] (trans only)
    unsigned short* z = (unsigned short*)(ewt + NEDGES);         // [3N*128] geo|cat|trans
    unsigned short* f_bf = (unsigned short*)d_out;   // [N*128] bf16, overwritten by k_final

    // zero cnt + w_part (contiguous)
    hipMemsetAsync(cnt, 0, (MTOT + 64)*sizeof(int), stream);

    k_cvt<<<64, 256, 0, stream>>>(aw1, w1_bf, 512*DD/4);
    k_transform<<<(NNODES/16 + 3)/4, 256, 0, stream>>>(feat, W, f_bf);

    int ebg = (NEDGES + 255)/256;                    // 2344
    k_hist<<<ebg, 256, 0, stream>>>(geo_dst,   cnt + 0*NNODES);
    k_hist<<<ebg, 256, 0, stream>>>(cat_dst,   cnt + 1*NNODES);
    k_hist<<<ebg, 256, 0, stream>>>(trans_dst, cnt + 2*NNODES);

    int nb = (MTOT + 1023)/1024;                     // 293
    k_scan1<<<nb, 256, 0, stream>>>(cnt, offs, bsum);
    k_scan2<<<1, 512, 0, stream>>>(bsum, nb);
    k_scan3<<<(MTOT + 255)/256, 256, 0, stream>>>(offs, cursor, bsum);

    k_fill<<<ebg, 256, 0, stream>>>(geo_src,   geo_dst,   nullptr, cursor + 0*NNODES, es, ewt);
    k_fill<<<ebg, 256, 0, stream>>>(cat_src,   cat_dst,   nullptr, cursor + 1*NNODES, es, ewt);
    k_fill<<<ebg, 256, 0, stream>>>(trans_src, trans_dst, tw,      cursor + 2*NNODES, es, ewt);

    k_agg<<<(MTOT*16 + 255)/256, 256, 0, stream>>>(f_bf, es, ewt, offs, cnt, z);

    unsigned short* z_geo   = z;
    unsigned short* z_cat   = z + (size_t)NNODES*DD;
    unsigned short* z_trans = z + (size_t)2*NNODES*DD;

    k_att<<<(3*(NNODES/32) + 3)/4, 256, 0, stream>>>(z_geo, z_trans, z_cat,
                                                     w1_bf, ab1, aw2, w_part);

    int dg = (NNODES*DD/4 + 255)/256;
    k_final<<<dg, 256, 0, stream>>>(z_geo, z_trans, z_cat, w_part, (float*)d_out);
}

// Round 5
// 593.231 us; speedup vs baseline: 11.3536x; 1.2510x over previous
//
#include <hip/hip_runtime.h>
#include <math.h>

#define DD 128
#define NNODES 100000
#define NEDGES 600000
#define NREL 3
#define MTOT (NREL*NNODES)
#define NTILES (NNODES/16)          // 6250 row-tiles per relation
#define RT_PER_BLK 8                // 128 rows per block
#define NBLK_REL ((NTILES + RT_PER_BLK - 1)/RT_PER_BLK)   // 782

typedef __attribute__((ext_vector_type(8))) short short8;
typedef __attribute__((ext_vector_type(4))) float f32x4;

__device__ inline float bf2f(unsigned short u){ return __uint_as_float(((unsigned int)u)<<16); }
__device__ inline float bflo(unsigned int u){ return __uint_as_float(u<<16); }
__device__ inline float bfhi(unsigned int u){ return __uint_as_float(u & 0xffff0000u); }
__device__ inline unsigned short f2bf(float f){          // RNE fp32->bf16
    unsigned int i = __float_as_uint(f);
    unsigned int r = (i + 0x7fffu + ((i>>16)&1u)) >> 16;
    return (unsigned short)r;
}
__device__ inline unsigned int pack2(float lo, float hi){
    return (unsigned int)f2bf(lo) | ((unsigned int)f2bf(hi) << 16);
}
__device__ inline short8 cvt8(const float* __restrict__ p){  // 8 fp32 -> bf16x8
    f32x4 a = *(const f32x4*)p;
    f32x4 b = *(const f32x4*)(p+4);
    short8 t;
    t[0]=(short)f2bf(a[0]); t[1]=(short)f2bf(a[1]); t[2]=(short)f2bf(a[2]); t[3]=(short)f2bf(a[3]);
    t[4]=(short)f2bf(b[0]); t[5]=(short)f2bf(b[1]); t[6]=(short)f2bf(b[2]); t[7]=(short)f2bf(b[3]);
    return t;
}

// ---- K0: convert att_w1 fp32 -> bf16 -----------------------------------------
__global__ __launch_bounds__(256) void k_cvt(const float* __restrict__ in,
                                             unsigned short* __restrict__ out, int n4)
{
    int gid = blockIdx.x*256 + threadIdx.x;
    if (gid >= n4) return;
    f32x4 v = ((const f32x4*)in)[gid];
    ushort4 o;
    o.x=f2bf(v[0]); o.y=f2bf(v[1]); o.z=f2bf(v[2]); o.w=f2bf(v[3]);
    ((ushort4*)out)[gid] = o;
}

// ---- K1: f = feat @ W^T  (fp32 in -> bf16 MFMA -> bf16 out) ------------------
__global__ __launch_bounds__(256) void k_transform(
    const float* __restrict__ feat, const float* __restrict__ W,
    unsigned short* __restrict__ f_out)
{
    int wid = blockIdx.x*4 + (threadIdx.x>>6);
    if (wid >= NNODES/16) return;
    int lane = threadIdx.x & 63;
    int m = lane & 15, quad = lane >> 4;
    int n0 = wid*16;

    short8 a[4];                                   // A[m][k], k=ks*32+quad*8+j
    const float* arow = feat + (size_t)(n0+m)*DD;
    #pragma unroll
    for (int ks=0; ks<4; ++ks) a[ks] = cvt8(arow + ks*32 + quad*8);

    #pragma unroll
    for (int ct=0; ct<8; ++ct){
        f32x4 acc = {0.f,0.f,0.f,0.f};
        const float* brow = W + (size_t)(ct*16+m)*DD;   // B[k][n]=W[n][k]
        #pragma unroll
        for (int ks=0; ks<4; ++ks){
            short8 b = cvt8(brow + ks*32 + quad*8);
            acc = __builtin_amdgcn_mfma_f32_16x16x32_bf16(a[ks], b, acc, 0,0,0);
        }
        int col = ct*16 + m;
        #pragma unroll
        for (int i=0;i<4;++i)                      // C/D: col=lane&15, row=quad*4+reg
            f_out[(size_t)(n0+quad*4+i)*DD + col] = f2bf(acc[i]);
    }
}

// ---- CSR build: histogram ----------------------------------------------------
__global__ __launch_bounds__(256) void k_hist(const int* __restrict__ dst,
                                              int* __restrict__ cnt_rel)
{
    int e = blockIdx.x*256 + threadIdx.x;
    if (e >= NEDGES) return;
    atomicAdd(&cnt_rel[dst[e]], 1);
}

// ---- CSR build: two-level exclusive scan over cnt[MTOT] ----------------------
__global__ __launch_bounds__(256) void k_scan1(const int* __restrict__ cnt,
                                               int* __restrict__ offs,
                                               int* __restrict__ bsum)
{
    __shared__ int sm[256];
    int t = threadIdx.x;
    int base = blockIdx.x*1024 + t*4;
    int v[4];
    #pragma unroll
    for (int i=0;i<4;++i){ int idx=base+i; v[i] = (idx<MTOT)? cnt[idx] : 0; }
    int tot = v[0]+v[1]+v[2]+v[3];
    sm[t] = tot; __syncthreads();
    for (int off=1; off<256; off<<=1){
        int x = (t>=off)? sm[t-off] : 0;
        __syncthreads();
        sm[t] += x;
        __syncthreads();
    }
    int run = (t>0)? sm[t-1] : 0;                 // exclusive within block
    if (t==255) bsum[blockIdx.x] = sm[255];
    #pragma unroll
    for (int i=0;i<4;++i){ int idx=base+i; if (idx<MTOT) offs[idx]=run; run += v[i]; }
}

__global__ __launch_bounds__(512) void k_scan2(int* __restrict__ bsum, int nb)
{
    __shared__ int sm[512];
    int t = threadIdx.x;
    sm[t] = (t<nb)? bsum[t] : 0; __syncthreads();
    for (int off=1; off<512; off<<=1){
        int x = (t>=off)? sm[t-off] : 0;
        __syncthreads();
        sm[t] += x;
        __syncthreads();
    }
    if (t<nb) bsum[t] = (t>0)? sm[t-1] : 0;       // exclusive
}

__global__ __launch_bounds__(256) void k_scan3(int* __restrict__ offs,
                                               int* __restrict__ cursor,
                                               const int* __restrict__ bsum)
{
    int g = blockIdx.x*256 + threadIdx.x;
    if (g >= MTOT) return;
    int v = offs[g] + bsum[g>>10];
    offs[g] = v;
    cursor[g] = v;
}

// ---- CSR build: fill edge lists ---------------------------------------------
__global__ __launch_bounds__(256) void k_fill(
    const int* __restrict__ src, const int* __restrict__ dst,
    const float* __restrict__ w,            // null for unweighted
    int* __restrict__ cursor_rel,           // cursor + rel*N
    int* __restrict__ es, float* __restrict__ ewt)
{
    int e = blockIdx.x*256 + threadIdx.x;
    if (e >= NEDGES) return;
    int d = dst[e];
    int pos = atomicAdd(&cursor_rel[d], 1);
    es[pos] = src[e];
    if (w) ewt[pos - 2*NEDGES] = w[e];      // weighted relation occupies [2E,3E)
}

// ---- K2: gather-side aggregation, one 16-lane group per (rel,node) -----------
__global__ __launch_bounds__(256) void k_agg(
    const unsigned short* __restrict__ f,   // bf16 [N,128]
    const int* __restrict__ es, const float* __restrict__ ewt,
    const int* __restrict__ offs, const int* __restrict__ cnt,
    unsigned short* __restrict__ z)         // bf16 [3,N,128]: geo|cat|trans
{
    int gid = blockIdx.x*256 + threadIdx.x;
    int g = gid >> 4;                        // (rel,node) slot in [0, 3N)
    if (g >= MTOT) return;
    int c = gid & 15;                        // 8-col chunk
    int rel = g / NNODES;                    // 0 geo, 1 cat, 2 trans (weighted)
    int start = offs[g];
    int deg   = cnt[g];

    float a0=0,a1=0,a2=0,a3=0,a4=0,a5=0,a6=0,a7=0;
    int i = 0;
    for (; i+1 < deg; i += 2){               // 2 outstanding gathers
        int s0 = es[start+i], s1 = es[start+i+1];
        uint4 v0 = *(const uint4*)(f + (size_t)s0*DD + c*8);
        uint4 v1 = *(const uint4*)(f + (size_t)s1*DD + c*8);
        float w0 = (rel==2) ? ewt[start+i   - 2*NEDGES] : 1.f;
        float w1 = (rel==2) ? ewt[start+i+1 - 2*NEDGES] : 1.f;
        a0 += w0*bflo(v0.x); a1 += w0*bfhi(v0.x);
        a2 += w0*bflo(v0.y); a3 += w0*bfhi(v0.y);
        a4 += w0*bflo(v0.z); a5 += w0*bfhi(v0.z);
        a6 += w0*bflo(v0.w); a7 += w0*bfhi(v0.w);
        a0 += w1*bflo(v1.x); a1 += w1*bfhi(v1.x);
        a2 += w1*bflo(v1.y); a3 += w1*bfhi(v1.y);
        a4 += w1*bflo(v1.z); a5 += w1*bfhi(v1.z);
        a6 += w1*bflo(v1.w); a7 += w1*bfhi(v1.w);
    }
    if (i < deg){
        int s = es[start+i];
        float w = (rel==2) ? ewt[start+i - 2*NEDGES] : 1.f;
        uint4 v = *(const uint4*)(f + (size_t)s*DD + c*8);
        a0 += w*bflo(v.x); a1 += w*bfhi(v.x);
        a2 += w*bflo(v.y); a3 += w*bfhi(v.y);
        a4 += w*bflo(v.z); a5 += w*bfhi(v.z);
        a6 += w*bflo(v.w); a7 += w*bfhi(v.w);
    }
    float sc = (rel<2) ? 1.f/fmaxf((float)deg, 1.f) : 1.f;
    uint4 o;
    o.x = pack2(a0*sc, a1*sc);
    o.y = pack2(a2*sc, a3*sc);
    o.z = pack2(a4*sc, a5*sc);
    o.w = pack2(a6*sc, a7*sc);
    *(uint4*)(z + (size_t)g*DD + c*8) = o;
}

// ---- K4: w_part[rel] = sum_n w2 . tanh(W1 z_n + b1) --------------------------
// Block: 4 waves, 128 rows of one relation; z tile staged in LDS (XOR-swizzled);
// each wave owns 128 cols (8 col-tiles), B-frags in registers per col-tile.
// tanh(x) = 1 - 2*rcp(exp2(C2*x)+1), C2 = 2*log2(e): no clamp needed.
__global__ __launch_bounds__(256) void k_att(
    const unsigned short* __restrict__ z,    // bf16 [3,N,128]
    const unsigned short* __restrict__ w1,   // bf16 [512,128]
    const float* __restrict__ bias1,         // fp32 [512]
    const float* __restrict__ wv2,           // fp32 [512]
    float* __restrict__ w_part)              // fp32 [3] (memory-relation order)
{
    __shared__ uint4 sm[RT_PER_BLK*256];     // 32 KB: unit(rt,kc,m) = rt*256+kc*16+(m^kc)
    const float C2 = 2.8853900817779268f;    // 2*log2(e)

    int rel = blockIdx.x / NBLK_REL;
    int nb  = blockIdx.x % NBLK_REL;
    int trt0 = nb * RT_PER_BLK;
    int rt_count = min(RT_PER_BLK, NTILES - trt0);
    int row0 = trt0 * 16;
    const unsigned short* zrel = z + (size_t)rel*NNODES*DD;

    int valid_rows = rt_count * 16;
    #pragma unroll
    for (int i=0; i<8; ++i){
        int u = i*256 + threadIdx.x;         // [row(128)][kc(16)]
        int row = u >> 4, kc = u & 15;
        if (row < valid_rows){
            uint4 v = *(const uint4*)(zrel + (size_t)(row0+row)*DD + kc*8);
            int rt = row >> 4, m = row & 15;
            sm[rt*256 + kc*16 + (m ^ kc)] = v;
        }
    }
    __syncthreads();

    int lane = threadIdx.x & 63;
    int wv   = threadIdx.x >> 6;             // wave 0..3 -> cols [wv*128, wv*128+128)
    int m = lane & 15, quad = lane >> 4;
    const short8* smx = (const short8*)sm;

    float s_all = 0.f;
    #pragma unroll
    for (int ct=0; ct<8; ++ct){
        int col = (wv*8 + ct)*16 + m;
        const short8* brow = (const short8*)(w1 + (size_t)col*DD);
        short8 bf0 = brow[quad];             // ks*4+quad, ks=0..3
        short8 bf1 = brow[4 + quad];
        short8 bf2 = brow[8 + quad];
        short8 bf3 = brow[12 + quad];
        float ww  = wv2[col];
        float bbc = bias1[col] * C2;

        float s_r = 0.f;
        for (int rt=0; rt<rt_count; ++rt){
            int base = rt*256;
            short8 a0 = smx[base + (0 + quad)*16 + (m ^ (0 + quad))];
            short8 a1 = smx[base + (4 + quad)*16 + (m ^ (4 + quad))];
            short8 a2 = smx[base + (8 + quad)*16 + (m ^ (8 + quad))];
            short8 a3 = smx[base + (12 + quad)*16 + (m ^ (12 + quad))];
            f32x4 acc = {0.f,0.f,0.f,0.f};
            acc = __builtin_amdgcn_mfma_f32_16x16x32_bf16(a0, bf0, acc, 0,0,0);
            acc = __builtin_amdgcn_mfma_f32_16x16x32_bf16(a1, bf1, acc, 0,0,0);
            acc = __builtin_amdgcn_mfma_f32_16x16x32_bf16(a2, bf2, acc, 0,0,0);
            acc = __builtin_amdgcn_mfma_f32_16x16x32_bf16(a3, bf3, acc, 0,0,0);
            #pragma unroll
            for (int i=0;i<4;++i){
                float e = __builtin_amdgcn_exp2f(__builtin_fmaf(acc[i], C2, bbc));
                s_r += __builtin_amdgcn_rcpf(e + 1.f);
            }
        }
        // sum of ww*(1 - 2r) over 4*rt_count values
        s_all += ww * (float)(4*rt_count) - 2.f*ww*s_r;
    }
    #pragma unroll
    for (int off=32; off; off>>=1) s_all += __shfl_xor(s_all, off);
    if (lane == 0) atomicAdd(&w_part[rel], s_all);
}

// ---- K5: softmax(3) + fuse + leaky relu, fp32 out ----------------------------
__global__ __launch_bounds__(256) void k_final(
    const unsigned short* __restrict__ z0, const unsigned short* __restrict__ z1,
    const unsigned short* __restrict__ z2,
    const float* __restrict__ w_part, float* __restrict__ out)
{
    int gid = blockIdx.x*256 + threadIdx.x;      // one per 4 elements
    if (gid >= NNODES*DD/4) return;
    const float invN = 1.f / (float)NNODES;
    float w0 = w_part[0]*invN, w1 = w_part[1]*invN, w2 = w_part[2]*invN;
    float mx = fmaxf(w0, fmaxf(w1, w2));
    const float LOG2E = 1.4426950408889634f;
    float e0 = __builtin_amdgcn_exp2f((w0-mx)*LOG2E);
    float e1 = __builtin_amdgcn_exp2f((w1-mx)*LOG2E);
    float e2 = __builtin_amdgcn_exp2f((w2-mx)*LOG2E);
    float inv = 1.f/(e0+e1+e2);
    float b0 = e0*inv, b1 = e1*inv, b2 = e2*inv;
    ushort4 g = ((const ushort4*)z0)[gid];
    ushort4 t = ((const ushort4*)z1)[gid];
    ushort4 c = ((const ushort4*)z2)[gid];
    f32x4 o;
    float gv[4] = {bf2f(g.x),bf2f(g.y),bf2f(g.z),bf2f(g.w)};
    float tv[4] = {bf2f(t.x),bf2f(t.y),bf2f(t.z),bf2f(t.w)};
    float cv[4] = {bf2f(c.x),bf2f(c.y),bf2f(c.z),bf2f(c.w)};
    #pragma unroll
    for (int i=0;i<4;++i){
        float x = b0*gv[i] + b1*tv[i] + b2*cv[i];
        o[i] = (x > 0.f) ? x : 0.2f*x;
    }
    ((f32x4*)out)[gid] = o;
}

extern "C" void kernel_launch(void* const* d_in, const int* in_sizes, int n_in,
                              void* d_out, int out_size, void* d_ws, size_t ws_size,
                              hipStream_t stream)
{
    const float* feat = (const float*)d_in[0];
    const float* W    = (const float*)d_in[1];
    const float* aw1  = (const float*)d_in[2];
    const float* ab1  = (const float*)d_in[3];
    const float* aw2  = (const float*)d_in[4];
    const float* tw   = (const float*)d_in[5];
    const int* geo_src   = (const int*)d_in[6];
    const int* geo_dst   = (const int*)d_in[7];
    const int* cat_src   = (const int*)d_in[8];
    const int* cat_dst   = (const int*)d_in[9];
    const int* trans_src = (const int*)d_in[10];
    const int* trans_dst = (const int*)d_in[11];

    // ws layout (~91 MB): cnt | w_part | offs | cursor | bsum | w1_bf | es | ewt | z
    char* ws = (char*)d_ws;
    int*   cnt    = (int*)ws;                        // [3N]
    float* w_part = (float*)(cnt + MTOT);            // [64]
    int*   offs   = (int*)(w_part + 64);             // [3N]
    int*   cursor = offs + MTOT;                     // [3N]
    int*   bsum   = cursor + MTOT;                   // [512]
    unsigned short* w1_bf = (unsigned short*)(bsum + 512);       // [512*128]
    int*   es     = (int*)(w1_bf + 512*DD);          // [3E]
    float* ewt    = (float*)(es + NREL*NEDGES);      // [E] (trans only)
    unsigned short* z = (unsigned short*)(ewt + NEDGES);         // [3N*128] geo|cat|trans
    unsigned short* f_bf = (unsigned short*)d_out;   // [N*128] bf16, overwritten by k_final

    // zero cnt + w_part (contiguous)
    (void)hipMemsetAsync(cnt, 0, (MTOT + 64)*sizeof(int), stream);

    k_cvt<<<64, 256, 0, stream>>>(aw1, w1_bf, 512*DD/4);
    k_transform<<<(NNODES/16 + 3)/4, 256, 0, stream>>>(feat, W, f_bf);

    int ebg = (NEDGES + 255)/256;                    // 2344
    k_hist<<<ebg, 256, 0, stream>>>(geo_dst,   cnt + 0*NNODES);
    k_hist<<<ebg, 256, 0, stream>>>(cat_dst,   cnt + 1*NNODES);
    k_hist<<<ebg, 256, 0, stream>>>(trans_dst, cnt + 2*NNODES);

    int nb = (MTOT + 1023)/1024;                     // 293
    k_scan1<<<nb, 256, 0, stream>>>(cnt, offs, bsum);
    k_scan2<<<1, 512, 0, stream>>>(bsum, nb);
    k_scan3<<<(MTOT + 255)/256, 256, 0, stream>>>(offs, cursor, bsum);

    k_fill<<<ebg, 256, 0, stream>>>(geo_src,   geo_dst,   nullptr, cursor + 0*NNODES, es, ewt);
    k_fill<<<ebg, 256, 0, stream>>>(cat_src,   cat_dst,   nullptr, cursor + 1*NNODES, es, ewt);
    k_fill<<<ebg, 256, 0, stream>>>(trans_src, trans_dst, tw,      cursor + 2*NNODES, es, ewt);

    k_agg<<<(MTOT*16 + 255)/256, 256, 0, stream>>>(f_bf, es, ewt, offs, cnt, z);

    // k_att over memory-relation order (0=geo, 1=cat, 2=trans)
    k_att<<<NREL*NBLK_REL, 256, 0, stream>>>(z, w1_bf, ab1, aw2, w_part);

    // pairing consistent with k_att: w_part[0]<->geo, [1]<->cat, [2]<->trans
    unsigned short* z_geo   = z;
    unsigned short* z_cat   = z + (size_t)NNODES*DD;
    unsigned short* z_trans = z + (size_t)2*NNODES*DD;
    int dg = (NNODES*DD/4 + 255)/256;
    k_final<<<dg, 256, 0, stream>>>(z_geo, z_cat, z_trans, w_part, (float*)d_out);
}